// Round 12
// baseline (363.235 us; speedup 1.0000x reference)
//
#include <hip/hip_runtime.h>
#include <hip/hip_bf16.h>
#include <math.h>

#define EPS 1e-5f

static constexpr int N_ = 128, C_ = 128, T_ = 256, V_ = 21, E_ = 8, M_ = 13;
static constexpr int TV_ = T_ * V_;   // 5376
static constexpr int NT_ = 4;         // t's per main-kernel tile
static constexpr int ST_ = NT_ * V_;  // 84 s-columns per tile
static constexpr int XF_PITCH = 48;   // bytes per xf row (24 bf16 slots, 21 used)

// staging swizzle: 16-slot spread keyed by (s>>3, s&7); bijective within each 256B row
#define SWZ(s)  (((((s) >> 3) & 15) ^ ((((s) & 7)) << 1)) << 4)
// xf row xor (bijective within 32-row groups; same on read & write)
#define EXOR(r) ((((r) >> 5) & 3) << 4)

typedef short bf16x8 __attribute__((ext_vector_type(8)));
typedef short s16x4  __attribute__((ext_vector_type(4)));
typedef float f32x4  __attribute__((ext_vector_type(4)));

__device__ inline short f2bf(float v) {
    __hip_bfloat16 b = __float2bfloat16(v);
    return *reinterpret_cast<short*>(&b);
}
__device__ inline float bf2f_u(unsigned short s) {
    __hip_bfloat16 b = *reinterpret_cast<__hip_bfloat16*>(&s);
    return __bfloat162float(b);
}

// ---------------- Kernel P: fold BN + convert W to bf16 ----------------
__global__ __launch_bounds__(256) void prep_kernel(
    const float* __restrict__ ft_w, const float* __restrict__ ft_b,
    const float* __restrict__ ft_gamma, const float* __restrict__ ft_beta,
    const float* __restrict__ ft_mean, const float* __restrict__ ft_var,
    __hip_bfloat16* __restrict__ w_bf, float* __restrict__ sc_g, float* __restrict__ sh_g)
{
    int tid = blockIdx.x * 256 + threadIdx.x;
    if (tid < C_ * C_) w_bf[tid] = __float2bfloat16(ft_w[tid]);
    if (tid < C_) {
        float sc = ft_gamma[tid] * rsqrtf(ft_var[tid] + EPS);
        sc_g[tid] = sc;
        sh_g[tid] = (ft_b[tid] - ft_mean[tid]) * sc + ft_beta[tid];
    }
}

// ---------------- Kernel CV: x -> bf16 copy + mean over T ----------------
__global__ __launch_bounds__(256) void cvt_kernel(const float* __restrict__ x,
                                                  __hip_bfloat16* __restrict__ xbf,
                                                  float* __restrict__ xm) {
    __shared__ float slab[TV_];
    __shared__ float partial[V_ * 8];
    const int nc = blockIdx.x;
    const int tid = threadIdx.x;
    const f32x4* src4 = (const f32x4*)(x + (size_t)nc * TV_);
    f32x4* slab4 = (f32x4*)slab;
    short* dst = (short*)xbf + (size_t)nc * TV_;

    #pragma unroll
    for (int it = 0; it < 3; ++it) {
        int p = it * 256 + tid;            // pair index (<672 valid)
        if (p < 672) {
            f32x4 a = src4[2 * p], b = src4[2 * p + 1];
            slab4[2 * p] = a; slab4[2 * p + 1] = b;
            bf16x8 pk = { f2bf(a[0]), f2bf(a[1]), f2bf(a[2]), f2bf(a[3]),
                          f2bf(b[0]), f2bf(b[1]), f2bf(b[2]), f2bf(b[3]) };
            *(bf16x8*)(dst + 8 * p) = pk;
        }
    }
    __syncthreads();
    if (tid < V_ * 8) {
        int v = tid >> 3, g = tid & 7;
        float s = 0.f;
        #pragma unroll
        for (int tt = 0; tt < 32; ++tt) s += slab[(g * 32 + tt) * V_ + v];
        partial[v * 8 + g] = s;
    }
    __syncthreads();
    if (tid < V_) {
        float s = 0.f;
        #pragma unroll
        for (int g = 0; g < 8; ++g) s += partial[tid * 8 + g];
        xm[(size_t)nc * V_ + tid] = s * (1.0f / T_);
    }
}

// ---------------- Kernel B: H_dyn + A = H^T H (bf16, 32x32 zero-padded) ----------------
__global__ __launch_bounds__(64) void hyper_kernel(
    const float* __restrict__ xm, const float* __restrict__ dyn_w,
    const float* __restrict__ dyn_b,
    const float* __restrict__ dyn_gamma, const float* __restrict__ dyn_beta,
    const float* __restrict__ dyn_mean, const float* __restrict__ dyn_var,
    __hip_bfloat16* __restrict__ A_bf)
{
    __shared__ float xs[C_ * V_];
    __shared__ float Hs[M_ * V_];
    const int n = blockIdx.x;
    const int l = threadIdx.x;
    const float* src = xm + (size_t)n * C_ * V_;
    for (int idx = l; idx < C_ * V_; idx += 64) xs[idx] = src[idx];
    __syncthreads();
    for (int idx = l; idx < E_ * V_; idx += 64) {
        int e = idx / V_, v = idx - e * V_;
        float acc = 0.f;
        for (int c = 0; c < C_; ++c) acc = fmaf(xs[c * V_ + v], dyn_w[e * C_ + c], acc);
        acc += dyn_b[e];
        float scale = dyn_gamma[e] * rsqrtf(dyn_var[e] + EPS);
        acc = (acc - dyn_mean[e]) * scale + dyn_beta[e];
        Hs[idx] = fmaxf(acc, 0.f);
    }
    __syncthreads();
    if (l < E_) {
        float row[V_];
        float mx = -1e30f;
        #pragma unroll
        for (int v = 0; v < V_; ++v) { row[v] = Hs[l * V_ + v]; mx = fmaxf(mx, row[v]); }
        float s = 0.f;
        #pragma unroll
        for (int v = 0; v < V_; ++v) { row[v] = __expf(row[v] - mx); s += row[v]; }
        float inv = 1.0f / s;
        #pragma unroll
        for (int v = 0; v < V_; ++v) Hs[l * V_ + v] = row[v] * inv;
    } else if (l < M_) {
        int i = l - E_;
        #pragma unroll
        for (int v = 0; v < V_; ++v)
            Hs[l * V_ + v] = (v >= 1 + 4 * i && v < 5 + 4 * i) ? 1.0f : 0.0f;
    }
    __syncthreads();
    for (int idx = l; idx < 32 * 32; idx += 64) {
        int u = idx >> 5, v = idx & 31;
        float s = 0.f;
        if (u < V_ && v < V_) {
            #pragma unroll
            for (int m = 0; m < M_; ++m) s = fmaf(Hs[m * V_ + u], Hs[m * V_ + v], s);
        }
        A_bf[(size_t)n * 1024 + idx] = __float2bfloat16(s);
    }
}

// ---------------- Kernel C: MFMA GEMM + BN/ReLU + MFMA A-transform + residual ----------------
// NT=4 variant of the proven round-11 structure: half the tile, half the LDS -> 3-4 blocks/CU.
// grid (64 s-tiles, 128 n), 512 threads = 8 waves. Wave w owns o in [16w, 16w+16).
__global__ __launch_bounds__(512, 6) void main_kernel(
    const __hip_bfloat16* __restrict__ xbf, const __hip_bfloat16* __restrict__ w_bf,
    const float* __restrict__ sc_g, const float* __restrict__ sh_g,
    const __hip_bfloat16* __restrict__ A_bf, float* __restrict__ out)
{
    // phase 1: X_t[s=96][c=128] bf16 swizzled (24576 B)
    // phase 2: xf[(o*4+t)=512][24 bf16] pitch 48 B (24576 B, overlays) + 64 B zeroed tail
    __shared__ __align__(16) char lds[24640];
    __shared__ float sc_s[C_], sh_s[C_];

    const int st = blockIdx.x;
    const int n  = blockIdx.y;
    const int tid = threadIdx.x;
    const int w = tid >> 6;       // wave 0..7
    const int l = tid & 63;
    const int hi = l >> 4;        // 0..3
    const int lo = l & 15;
    const int s0 = st * ST_;
    const unsigned short* xr = (const unsigned short*)xbf + (size_t)n * C_ * TV_;
    float* ob = out + (size_t)n * C_ * TV_;

    if (tid < C_) { sc_s[tid] = sc_g[tid]; sh_s[tid] = sh_g[tid]; }

    // W fragments (GEMM1 A-operand): lane holds W[16w+lo][kk*32 + 8*hi + j]
    const int o_row = 16 * w + lo;
    bf16x8 wf[4];
    #pragma unroll
    for (int kk = 0; kk < 4; ++kk)
        wf[kk] = *(const bf16x8*)((const short*)w_bf + o_row * C_ + kk * 32 + 8 * hi);

    // GEMM2 B-fragments (A symmetric, zero-padded 32x32, L2-hot)
    const short* An = (const short*)A_bf + n * 1024;
    const bf16x8 bA0 = *(const bf16x8*)(An + lo * 32 + 8 * hi);         // v = 0..15
    const bf16x8 bA1 = *(const bf16x8*)(An + (16 + lo) * 32 + 8 * hi);  // v = 16..31

    // ---- stage X_t[s][c]: 336 items of 8c x 4s (8x8B loads -> 4x ds_write_b128) ----
    if (tid < 336) {
        int cg = tid / 21, q = tid - 21 * cg;   // cg: 8-channel group, q: 4-s granule
        int c0 = 8 * cg, sb = 4 * q;
        const unsigned short* p = xr + c0 * TV_ + s0 + sb;
        s16x4 v[8];
        #pragma unroll
        for (int j = 0; j < 8; ++j) v[j] = *(const s16x4*)(p + j * TV_);
        #pragma unroll
        for (int si = 0; si < 4; ++si) {
            int s = sb + si;
            bf16x8 pk = { v[0][si], v[1][si], v[2][si], v[3][si],
                          v[4][si], v[5][si], v[6][si], v[7][si] };
            *(bf16x8*)(lds + ((s * 256 + 16 * cg) ^ SWZ(s))) = pk;
        }
    }
    // zero pad rows s = 84..95 (XOR permutes within rows -> linear zero covers them)
    if (tid < 192) *(f32x4*)(lds + 84 * 256 + 16 * tid) = (f32x4){0.f, 0.f, 0.f, 0.f};
    __syncthreads();

    // ---- GEMM1: 6 N-frags, K = 128 in 4 steps ----
    f32x4 acc[6];
    #pragma unroll
    for (int nf = 0; nf < 6; ++nf) acc[nf] = (f32x4){0.f, 0.f, 0.f, 0.f};
    #pragma unroll
    for (int kk = 0; kk < 4; ++kk) {
        #pragma unroll
        for (int nf = 0; nf < 6; ++nf) {
            int srow = 16 * nf + lo;
            bf16x8 b = *(const bf16x8*)(lds + ((srow * 256 + (kk * 32 + 8 * hi) * 2) ^ SWZ(srow)));
            acc[nf] = __builtin_amdgcn_mfma_f32_16x16x32_bf16(wf[kk], b, acc[nf], 0, 0, 0);
        }
    }
    __syncthreads();   // staging reads complete; buffer becomes xf

    // ---- BN + ReLU -> xf bf16 at row (o*4+t), pitch 48 B, row-xor EXOR ----
    const int obase = 16 * w + 4 * hi;
    float scr[4], shr[4];
    #pragma unroll
    for (int r = 0; r < 4; ++r) { scr[r] = sc_s[obase + r]; shr[r] = sh_s[obase + r]; }
    #pragma unroll
    for (int nf = 0; nf < 6; ++nf) {
        int s = 16 * nf + lo;
        if (s < ST_) {
            int t = s / V_, u = s - t * V_;
            #pragma unroll
            for (int r = 0; r < 4; ++r) {
                float vv = fmaxf(fmaf(acc[nf][r], scr[r], shr[r]), 0.f);
                int row = (obase + r) * NT_ + t;
                *(short*)(lds + ((row * XF_PITCH + 2 * u) ^ EXOR(row))) = f2bf(vv);
            }
        }
    }
    // zero u=21..23 pad of this thread's row + 64 B tail (finite for k>=21 reads)
    {
        int row = tid;             // 512 threads == 512 rows
        *(short*)(lds + ((row * XF_PITCH + 42) ^ EXOR(row))) = 0;
        *(int*)(lds + ((row * XF_PITCH + 44) ^ EXOR(row))) = 0;
    }
    if (tid < 4) *(f32x4*)(lds + 24576 + 16 * tid) = (f32x4){0.f, 0.f, 0.f, 0.f};
    __syncthreads();

    // ---- GEMM2: Xr = xf (512x32) * A (32x32); wave w owns M-frags 4w..4w+3 ----
    bf16x8 xfr[4];
    #pragma unroll
    for (int i = 0; i < 4; ++i) {
        int lr = 16 * (4 * w + i) + lo;
        xfr[i] = *(const bf16x8*)(lds + ((lr * XF_PITCH + 16 * hi) ^ EXOR(lr)));
    }
    #pragma unroll
    for (int i = 0; i < 4; ++i) {
        f32x4 d0 = (f32x4){0.f, 0.f, 0.f, 0.f};
        f32x4 d1 = (f32x4){0.f, 0.f, 0.f, 0.f};
        d0 = __builtin_amdgcn_mfma_f32_16x16x32_bf16(xfr[i], bA0, d0, 0, 0, 0);
        d1 = __builtin_amdgcn_mfma_f32_16x16x32_bf16(xfr[i], bA1, d1, 0, 0, 0);
        int row0 = 16 * (4 * w + i) + 4 * hi;
        #pragma unroll
        for (int r = 0; r < 4; ++r) {
            int row = row0 + r;
            int o = row >> 2, tl = row & 3;
            int g = o * TV_ + s0 + tl * V_;       // 32-bit offset from per-n base
            ob[g + lo] = d0[r] + bf2f_u(xr[g + lo]);
            if (lo < V_ - 16) ob[g + 16 + lo] = d1[r] + bf2f_u(xr[g + 16 + lo]);
        }
    }
}

extern "C" void kernel_launch(void* const* d_in, const int* in_sizes, int n_in,
                              void* d_out, int out_size, void* d_ws, size_t ws_size,
                              hipStream_t stream) {
    const float* x         = (const float*)d_in[0];
    const float* dyn_w     = (const float*)d_in[1];
    const float* dyn_b     = (const float*)d_in[2];
    const float* dyn_gamma = (const float*)d_in[3];
    const float* dyn_beta  = (const float*)d_in[4];
    const float* dyn_mean  = (const float*)d_in[5];
    const float* dyn_var   = (const float*)d_in[6];
    const float* ft_w      = (const float*)d_in[7];
    const float* ft_b      = (const float*)d_in[8];
    const float* ft_gamma  = (const float*)d_in[9];
    const float* ft_beta   = (const float*)d_in[10];
    const float* ft_mean   = (const float*)d_in[11];
    const float* ft_var    = (const float*)d_in[12];
    float* out = (float*)d_out;

    char* ws = (char*)d_ws;
    float* xm  = (float*)ws;                     ws += (size_t)N_ * C_ * V_ * 4;
    __hip_bfloat16* A_bf = (__hip_bfloat16*)ws;  ws += (size_t)N_ * 1024 * 2;
    __hip_bfloat16* w_bf = (__hip_bfloat16*)ws;  ws += (size_t)C_ * C_ * 2;
    float* sc_g = (float*)ws;                    ws += C_ * 4;
    float* sh_g = (float*)ws;                    ws += C_ * 4;
    __hip_bfloat16* xbf = (__hip_bfloat16*)ws;   // 172 MB

    prep_kernel<<<64, 256, 0, stream>>>(ft_w, ft_b, ft_gamma, ft_beta, ft_mean, ft_var,
                                        w_bf, sc_g, sh_g);
    cvt_kernel<<<N_ * C_, 256, 0, stream>>>(x, xbf, xm);
    hyper_kernel<<<N_, 64, 0, stream>>>(xm, dyn_w, dyn_b, dyn_gamma, dyn_beta,
                                        dyn_mean, dyn_var, A_bf);
    main_kernel<<<dim3(T_ / NT_, 128), 512, 0, stream>>>(xbf, w_bf, sc_g, sh_g, A_bf, out);
}